// Round 7
// baseline (38.662 us; speedup 1.0000x reference)
//
#include <hip/hip_runtime.h>

#define ETA 0.5f
#define NTHREADS 256
#define UNROLL 4
#define CHUNK (NTHREADS * UNROLL)   // float4 elements per block-chunk (1024)
#define NCHUNKS 4                   // chunks per block (contiguous range)
#define NACC 5
#define WS_PARTIAL_OFF 64           // floats; ticket counter lives at ws[0]

__device__ __forceinline__ float wave_reduce_sum(float v) {
#pragma unroll
    for (int off = 32; off > 0; off >>= 1)
        v += __shfl_down(v, off, 64);
    return v;
}

// accumulators: sAll=Σs, sT=Σt*s, sA=Σ|t|*s, cT=Σt, cA=Σ|t|   (t ∈ {-1,0,1})
__device__ __forceinline__ void pnu_accum(float yy, int tt,
                                          float& sAll, float& sT, float& sA,
                                          float& cT, float& cA) {
    float s = __builtin_amdgcn_rcpf(1.0f + __expf(-yy));  // sigmoid(y)
    float tf = (float)tt;
    float ta = fabsf(tf);
    sAll += s;
    sT = fmaf(tf, s, sT);
    sA = fmaf(ta, s, sA);
    cT += tf;
    cA += ta;
}

#define LOAD_CHUNK(YB, TB, c)                                                \
    do {                                                                     \
        const int base_ = (c) * CHUNK + threadIdx.x;                         \
        _Pragma("unroll")                                                    \
        for (int u = 0; u < UNROLL; ++u) YB[u] = y4[base_ + u * NTHREADS];   \
        _Pragma("unroll")                                                    \
        for (int u = 0; u < UNROLL; ++u) TB[u] = t4[base_ + u * NTHREADS];   \
    } while (0)

#define COMPUTE_CHUNK(YB, TB)                                                \
    do {                                                                     \
        _Pragma("unroll")                                                    \
        for (int u = 0; u < UNROLL; ++u) {                                   \
            pnu_accum(YB[u].x, TB[u].x, sAll, sT, sA, cT, cA);               \
            pnu_accum(YB[u].y, TB[u].y, sAll, sT, sA, cT, cA);               \
            pnu_accum(YB[u].z, TB[u].z, sAll, sT, sA, cT, cA);               \
            pnu_accum(YB[u].w, TB[u].w, sAll, sT, sA, cT, cA);               \
        }                                                                    \
    } while (0)

__global__ __launch_bounds__(NTHREADS, 4) void pnu_fused_kernel(
    const float* __restrict__ y, const int* __restrict__ t,
    const float* __restrict__ p_ratio, float* __restrict__ out,
    float* __restrict__ ws, int n, int nblocks, int nfull, int cpb) {
    const int nvec = n >> 2;
    const float4* __restrict__ y4 = reinterpret_cast<const float4*>(y);
    const int4* __restrict__ t4 = reinterpret_cast<const int4*>(t);
    float* __restrict__ partials = ws + WS_PARTIAL_OFF;
    unsigned* __restrict__ counter = reinterpret_cast<unsigned*>(ws);

    float sAll = 0.f, sT = 0.f, sA = 0.f, cT = 0.f, cA = 0.f;

    // contiguous chunk range per block, 2-deep software pipeline
    {
        int c = blockIdx.x * cpb;
        int end = c + cpb;
        if (end > nfull) end = nfull;
        if (c < end) {
            float4 yvA[UNROLL], yvB[UNROLL];
            int4 tvA[UNROLL], tvB[UNROLL];
            LOAD_CHUNK(yvA, tvA, c);
            while (c + 2 <= end) {
                LOAD_CHUNK(yvB, tvB, c + 1);
                COMPUTE_CHUNK(yvA, tvA);
                if (c + 2 < end) LOAD_CHUNK(yvA, tvA, c + 2);
                COMPUTE_CHUNK(yvB, tvB);
                c += 2;
            }
            if (c < end) COMPUTE_CHUNK(yvA, tvA);  // odd count tail
        }
    }

    // remainder (vec + scalar), handled by the last block only
    if (blockIdx.x == gridDim.x - 1) {
        for (int i = nfull * CHUNK + threadIdx.x; i < nvec; i += NTHREADS) {
            float4 yv = y4[i];
            int4 tv = t4[i];
            pnu_accum(yv.x, tv.x, sAll, sT, sA, cT, cA);
            pnu_accum(yv.y, tv.y, sAll, sT, sA, cT, cA);
            pnu_accum(yv.z, tv.z, sAll, sT, sA, cT, cA);
            pnu_accum(yv.w, tv.w, sAll, sT, sA, cT, cA);
        }
        for (int i = (nvec << 2) + threadIdx.x; i < n; i += NTHREADS)
            pnu_accum(y[i], t[i], sAll, sT, sA, cT, cA);
    }

    // block reduction: wave shuffle -> LDS -> 5 outputs (SoA across blocks)
    float vals[NACC] = {sAll, sT, sA, cT, cA};
    __shared__ float red[NTHREADS / 64][NACC];
    const int lane = threadIdx.x & 63;
    const int wave = threadIdx.x >> 6;
#pragma unroll
    for (int k = 0; k < NACC; ++k) {
        float r = wave_reduce_sum(vals[k]);
        if (lane == 0) red[wave][k] = r;
    }
    __syncthreads();
    // coherence-point stores (RELAXED+AGENT: no fence, no L2 writeback op;
    // distinct addresses: no contention). All 5 issue from wave 0.
    if (threadIdx.x < NACC) {
        float r = 0.f;
#pragma unroll
        for (int w = 0; w < NTHREADS / 64; ++w) r += red[w][threadIdx.x];
        __hip_atomic_store(&partials[threadIdx.x * nblocks + blockIdx.x], r,
                           __ATOMIC_RELAXED, __HIP_MEMORY_SCOPE_AGENT);
    }
    // ticket: wave-local vmcnt(0) orders wave 0's stores before the ticket
    // (SOPP executes wave-wide regardless of exec mask). RELAXED: no fence.
    __shared__ unsigned sTicket;
    if (threadIdx.x == 0) {
        asm volatile("s_waitcnt vmcnt(0)" ::: "memory");
        sTicket = __hip_atomic_fetch_add(counter, 1u, __ATOMIC_RELAXED,
                                         __HIP_MEMORY_SCOPE_AGENT);
    }
    __syncthreads();
    if (sTicket != (unsigned)(nblocks - 1)) return;  // block-uniform

    // last block: coherent reads of all partials, then finalize
    float acc[NACC] = {0.f, 0.f, 0.f, 0.f, 0.f};
    for (int i = threadIdx.x; i < nblocks; i += NTHREADS) {
#pragma unroll
        for (int k = 0; k < NACC; ++k)
            acc[k] += __hip_atomic_load(&partials[k * nblocks + i],
                                        __ATOMIC_RELAXED,
                                        __HIP_MEMORY_SCOPE_AGENT);
    }
    __syncthreads();  // red[] reuse
#pragma unroll
    for (int k = 0; k < NACC; ++k) {
        float r = wave_reduce_sum(acc[k]);
        if (lane == 0) red[wave][k] = r;
    }
    __syncthreads();
    if (threadIdx.x == 0) {
        float tot[NACC];
#pragma unroll
        for (int k = 0; k < NACC; ++k) {
            float r = 0.f;
#pragma unroll
            for (int w = 0; w < NTHREADS / 64; ++w) r += red[w][k];
            tot[k] = r;
        }
        const float sAllT = tot[0], sTT = tot[1], sAT = tot[2];
        const float cTT = tot[3], cAT = tot[4];

        const float cP = 0.5f * (cAT + cTT);
        const float cN = 0.5f * (cAT - cTT);
        const float cU = (float)n - cAT;
        const float sPm = 0.5f * (sAT + sTT);   // Σ idx_p * sigmoid(y)
        const float sNm = 0.5f * (sAT - sTT);   // Σ idx_n * sigmoid(y)
        const float sUm = sAllT - sAT;          // Σ idx_u * sigmoid(y)
        const float sPp = cP - sPm;             // Σ idx_p * sigmoid(-y)

        const float nP = fmaxf(1.0f, cP);
        const float nN = fmaxf(1.0f, cN);
        const float nU = fmaxf(1.0f, cU);

        const float R_P_plus  = sPp / nP;
        const float R_P_minus = sPm / nP;
        const float R_N_minus = sNm / nN;
        const float R_U_minus = sUm / nU;

        const float pi0 = p_ratio[0], pi1 = p_ratio[1];
        const float R_PN = pi0 * R_P_plus + pi1 * R_N_minus;
        const float R_PU = pi0 * (R_P_plus - R_P_minus) + R_U_minus;

        out[0] = (1.0f - ETA) * R_PN + ETA * R_PU;
    }
}

extern "C" void kernel_launch(void* const* d_in, const int* in_sizes, int n_in,
                              void* d_out, int out_size, void* d_ws, size_t ws_size,
                              hipStream_t stream) {
    const float* y = (const float*)d_in[0];
    const int* t = (const int*)d_in[1];
    const float* p_ratio = (const float*)d_in[2];
    float* out = (float*)d_out;
    float* ws = (float*)d_ws;

    const int n = in_sizes[0];
    const int nvec = n >> 2;
    const int nfull = nvec / CHUNK;                       // 4096 for N=16M
    const bool tail = (nfull * CHUNK * 4) < n;

    int nblocks = (nfull + NCHUNKS - 1) / NCHUNKS;        // 1024 for N=16M
    if (nblocks < 1) nblocks = 1;
    (void)tail;

    // cap grid to workspace capacity (64 floats header + NACC per block)
    size_t cap = (ws_size / sizeof(float));
    cap = cap > WS_PARTIAL_OFF ? (cap - WS_PARTIAL_OFF) / NACC : 1;
    int maxblocks = (int)(cap < 1 ? 1 : cap);
    if (nblocks > maxblocks) nblocks = maxblocks;

    const int cpb = (nfull + nblocks - 1) / nblocks;      // chunks per block

    // zero the ticket counter (graph-capturable memset node)
    hipMemsetAsync(d_ws, 0, WS_PARTIAL_OFF * sizeof(float), stream);

    pnu_fused_kernel<<<nblocks, NTHREADS, 0, stream>>>(y, t, p_ratio, out, ws,
                                                       n, nblocks, nfull, cpb);
}

// Round 8
// 29.826 us; speedup vs baseline: 1.2963x; 1.2963x over previous
//
#include <hip/hip_runtime.h>

#define ETA 0.5f
#define NTHREADS 256
#define UNROLL 4
#define CHUNK (NTHREADS * UNROLL)   // float4 elements per block-chunk (1024)
#define NCHUNKS 4                   // chunks per block (contiguous range)
#define NACC 5

__device__ __forceinline__ float wave_reduce_sum(float v) {
#pragma unroll
    for (int off = 32; off > 0; off >>= 1)
        v += __shfl_down(v, off, 64);
    return v;
}

// accumulators: sAll=Σs, sT=Σt*s, sA=Σ|t|*s, cT=Σt, cA=Σ|t|   (t ∈ {-1,0,1})
__device__ __forceinline__ void pnu_accum(float yy, int tt,
                                          float& sAll, float& sT, float& sA,
                                          float& cT, float& cA) {
    float s = __builtin_amdgcn_rcpf(1.0f + __expf(-yy));  // sigmoid(y)
    float tf = (float)tt;
    float ta = fabsf(tf);
    sAll += s;
    sT = fmaf(tf, s, sT);
    sA = fmaf(ta, s, sA);
    cT += tf;
    cA += ta;
}

#define LOAD_CHUNK(YB, TB, c)                                                \
    do {                                                                     \
        const int base_ = (c) * CHUNK + threadIdx.x;                         \
        _Pragma("unroll")                                                    \
        for (int u = 0; u < UNROLL; ++u) YB[u] = y4[base_ + u * NTHREADS];   \
        _Pragma("unroll")                                                    \
        for (int u = 0; u < UNROLL; ++u) TB[u] = t4[base_ + u * NTHREADS];   \
    } while (0)

#define COMPUTE_CHUNK(YB, TB)                                                \
    do {                                                                     \
        _Pragma("unroll")                                                    \
        for (int u = 0; u < UNROLL; ++u) {                                   \
            pnu_accum(YB[u].x, TB[u].x, sAll, sT, sA, cT, cA);               \
            pnu_accum(YB[u].y, TB[u].y, sAll, sT, sA, cT, cA);               \
            pnu_accum(YB[u].z, TB[u].z, sAll, sT, sA, cT, cA);               \
            pnu_accum(YB[u].w, TB[u].w, sAll, sT, sA, cT, cA);               \
        }                                                                    \
    } while (0)

__global__ __launch_bounds__(NTHREADS, 4) void pnu_partial_kernel(
    const float* __restrict__ y, const int* __restrict__ t,
    float* __restrict__ partials, int n, int nblocks, int nfull, int cpb) {
    const int nvec = n >> 2;
    const float4* __restrict__ y4 = reinterpret_cast<const float4*>(y);
    const int4* __restrict__ t4 = reinterpret_cast<const int4*>(t);

    float sAll = 0.f, sT = 0.f, sA = 0.f, cT = 0.f, cA = 0.f;

    // contiguous chunk range per block, 2-deep software pipeline:
    // load chunk c+1 while computing chunk c (statically-named buffers)
    {
        int c = blockIdx.x * cpb;
        int end = c + cpb;
        if (end > nfull) end = nfull;
        if (c < end) {
            float4 yvA[UNROLL], yvB[UNROLL];
            int4 tvA[UNROLL], tvB[UNROLL];
            LOAD_CHUNK(yvA, tvA, c);
            while (c + 2 <= end) {
                LOAD_CHUNK(yvB, tvB, c + 1);
                COMPUTE_CHUNK(yvA, tvA);
                if (c + 2 < end) LOAD_CHUNK(yvA, tvA, c + 2);
                COMPUTE_CHUNK(yvB, tvB);
                c += 2;
            }
            if (c < end) COMPUTE_CHUNK(yvA, tvA);  // odd count tail
        }
    }

    // remainder (vec + scalar), handled by the last block only
    if (blockIdx.x == gridDim.x - 1) {
        for (int i = nfull * CHUNK + threadIdx.x; i < nvec; i += NTHREADS) {
            float4 yv = y4[i];
            int4 tv = t4[i];
            pnu_accum(yv.x, tv.x, sAll, sT, sA, cT, cA);
            pnu_accum(yv.y, tv.y, sAll, sT, sA, cT, cA);
            pnu_accum(yv.z, tv.z, sAll, sT, sA, cT, cA);
            pnu_accum(yv.w, tv.w, sAll, sT, sA, cT, cA);
        }
        for (int i = (nvec << 2) + threadIdx.x; i < n; i += NTHREADS)
            pnu_accum(y[i], t[i], sAll, sT, sA, cT, cA);
    }

    // block reduction: wave shuffle -> LDS -> 5 outputs (SoA across blocks)
    float vals[NACC] = {sAll, sT, sA, cT, cA};
    __shared__ float red[NTHREADS / 64][NACC];
    const int lane = threadIdx.x & 63;
    const int wave = threadIdx.x >> 6;
#pragma unroll
    for (int k = 0; k < NACC; ++k) {
        float r = wave_reduce_sum(vals[k]);
        if (lane == 0) red[wave][k] = r;
    }
    __syncthreads();
    if (threadIdx.x < NACC) {
        float r = 0.f;
#pragma unroll
        for (int w = 0; w < NTHREADS / 64; ++w) r += red[w][threadIdx.x];
        partials[threadIdx.x * nblocks + blockIdx.x] = r;
    }
}

#define FTHREADS 1024

__global__ __launch_bounds__(FTHREADS) void pnu_final_kernel(
    const float* __restrict__ partials, const float* __restrict__ p_ratio,
    float* __restrict__ out, int nblocks, int n) {
    float acc[NACC] = {0.f, 0.f, 0.f, 0.f, 0.f};
    for (int i = threadIdx.x; i < nblocks; i += FTHREADS) {
#pragma unroll
        for (int k = 0; k < NACC; ++k) acc[k] += partials[k * nblocks + i];
    }
    __shared__ float red[FTHREADS / 64][NACC];
    const int lane = threadIdx.x & 63;
    const int wave = threadIdx.x >> 6;
#pragma unroll
    for (int k = 0; k < NACC; ++k) {
        float r = wave_reduce_sum(acc[k]);
        if (lane == 0) red[wave][k] = r;
    }
    __syncthreads();
    if (threadIdx.x == 0) {
        float tot[NACC];
#pragma unroll
        for (int k = 0; k < NACC; ++k) {
            float r = 0.f;
#pragma unroll
            for (int w = 0; w < FTHREADS / 64; ++w) r += red[w][k];
            tot[k] = r;
        }
        const float sAll = tot[0], sT = tot[1], sA = tot[2];
        const float cT = tot[3], cA = tot[4];

        const float cP = 0.5f * (cA + cT);
        const float cN = 0.5f * (cA - cT);
        const float cU = (float)n - cA;
        const float sPm = 0.5f * (sA + sT);   // Σ idx_p * sigmoid(y)
        const float sNm = 0.5f * (sA - sT);   // Σ idx_n * sigmoid(y)
        const float sUm = sAll - sA;          // Σ idx_u * sigmoid(y)
        const float sPp = cP - sPm;           // Σ idx_p * sigmoid(-y)

        const float nP = fmaxf(1.0f, cP);
        const float nN = fmaxf(1.0f, cN);
        const float nU = fmaxf(1.0f, cU);

        const float R_P_plus  = sPp / nP;
        const float R_P_minus = sPm / nP;
        const float R_N_minus = sNm / nN;
        const float R_U_minus = sUm / nU;

        const float pi0 = p_ratio[0], pi1 = p_ratio[1];
        const float R_PN = pi0 * R_P_plus + pi1 * R_N_minus;
        const float R_PU = pi0 * (R_P_plus - R_P_minus) + R_U_minus;

        out[0] = (1.0f - ETA) * R_PN + ETA * R_PU;
    }
}

extern "C" void kernel_launch(void* const* d_in, const int* in_sizes, int n_in,
                              void* d_out, int out_size, void* d_ws, size_t ws_size,
                              hipStream_t stream) {
    const float* y = (const float*)d_in[0];
    const int* t = (const int*)d_in[1];
    const float* p_ratio = (const float*)d_in[2];
    float* out = (float*)d_out;
    float* partials = (float*)d_ws;

    const int n = in_sizes[0];
    const int nvec = n >> 2;
    const int nfull = nvec / CHUNK;                       // 4096 for N=16M
    const bool tail = (nfull * CHUNK * 4) < n;

    int nblocks = (nfull + NCHUNKS - 1) / NCHUNKS;        // 1024 for N=16M
    if (tail && nblocks < 1) nblocks = 1;
    if (nblocks < 1) nblocks = 1;

    // cap grid to workspace capacity
    int maxblocks = (int)(ws_size / (NACC * sizeof(float)));
    if (maxblocks < 1) maxblocks = 1;
    if (nblocks > maxblocks) nblocks = maxblocks;

    const int cpb = (nfull + nblocks - 1) / nblocks;      // chunks per block

    pnu_partial_kernel<<<nblocks, NTHREADS, 0, stream>>>(y, t, partials, n,
                                                         nblocks, nfull, cpb);
    pnu_final_kernel<<<1, FTHREADS, 0, stream>>>(partials, p_ratio, out, nblocks, n);
}